// Round 10
// baseline (215.617 us; speedup 1.0000x reference)
//
#include <hip/hip_runtime.h>

#define NB 4
#define SEQ 16384
#define D 64
#define NH 8
#define INNER 512

typedef float f4 __attribute__((ext_vector_type(4)));

// ws float-offsets
#define OFF_S    0                 // [NB][64][64]   S = K^T V
#define OFF_GT   (NB * 4096)       // [NB][64][64]   GT[e][d] = G[d][e]
#define OFF_PART (2 * NB * 4096)   // [2048][4096]   per-block K^T V partials

// ---------------------------------------------------------------------------
// kA: per-block partial S over 32 rows. 2048 blocks (512/batch), 256 thr.
// VGPR ~40 -> 8 blocks/CU co-resident (32 waves/CU). Contiguous f4 loads,
// no LDS, no atomics; coalesced 16 KB partial store per block.
// ---------------------------------------------------------------------------
__global__ __launch_bounds__(256) void kA(const float* __restrict__ keys,
                                          const float* __restrict__ values,
                                          float* __restrict__ part) {
    const int bid = blockIdx.x;
    const int b = bid >> 9;
    const int row0 = (bid & 511) * 32;
    const int t = threadIdx.x;
    const int di = t >> 4, ej = t & 15;
    const float* kp = keys   + ((size_t)b * SEQ + row0) * D + di * 4;
    const float* vp = values + ((size_t)b * SEQ + row0) * D + ej * 4;
    f4 acc[4];
    #pragma unroll
    for (int r = 0; r < 4; ++r) acc[r] = (f4)0.f;
    #pragma unroll 8
    for (int n = 0; n < 32; ++n) {
        f4 k4 = *(const f4*)(kp + n * D);
        f4 v4 = *(const f4*)(vp + n * D);
        #pragma unroll
        for (int r = 0; r < 4; ++r)
            acc[r] += k4[r] * v4;
    }
    float* pp = part + (size_t)bid * 4096;
    #pragma unroll
    for (int r = 0; r < 4; ++r)
        *(f4*)(pp + (di * 4 + r) * 64 + ej * 4) = acc[r];
}

// ---------------------------------------------------------------------------
// kB: reduce 512 partials/batch -> S[b]. 256 blocks = (b, quarter, p-chunk).
// Block sums 32 partials over 1024 elems (f4/thread), then 4 scalar
// atomicAdds/thread into S (16-way contention, 262k atomics total).
// ---------------------------------------------------------------------------
__global__ __launch_bounds__(256) void kB(const float* __restrict__ part,
                                          float* __restrict__ S) {
    const int bid = blockIdx.x;
    const int b  = bid >> 6;
    const int q  = (bid >> 4) & 3;
    const int pc = bid & 15;
    const int t = threadIdx.x;
    const int e0 = q * 1024 + t * 4;
    const float* pp = part + (size_t)(b * 512 + pc * 32) * 4096 + e0;
    f4 s = (f4)0.f;
    #pragma unroll 8
    for (int p = 0; p < 32; ++p)
        s += *(const f4*)(pp + (size_t)p * 4096);
    float* Sb = S + b * 4096 + e0;
    #pragma unroll
    for (int i = 0; i < 4; ++i)
        atomicAdd(&Sb[i], s[i]);
}

// ---------------------------------------------------------------------------
// kC: merged kC1+kC2. One block per (b,h), 256 thr, 16x16 grid of 4x4 tiles.
// m1: T = Wk_h S      (LDS T, stride-65 + row-group rotation)
// m2: U = T Wk_h^T    (LDS U, same layout)
// m3: M3 = Wq_h^T U   (overwrite T)
// m4: GT[b] += (1/N)*(M3 Wout_h^T)^T  (atomicAdd, 8-way over h)
// Element (row,col) of a rotated LDS array lives at:
//   row*65 + (col&~3) + (((col&3) + (row>>2)) & 3)
// ---------------------------------------------------------------------------
__global__ __launch_bounds__(256) void kC(const float* __restrict__ Wq,
                                          const float* __restrict__ Wk,
                                          const float* __restrict__ Wout,
                                          float* __restrict__ ws) {
    __shared__ float T[64 * 65];
    __shared__ float U[64 * 65];
    const int b = blockIdx.x >> 3, h = blockIdx.x & 7;
    const int t = threadIdx.x;
    const int di = t >> 4, ej = t & 15;
    const float* Sb  = ws + OFF_S + b * 4096;
    const float* Wkh = Wk + (size_t)h * 64 * D;

    // m1: T[d][i] = sum_j Wk_h[d][j] * S[j][i]
    {
        f4 acc[4];
        #pragma unroll
        for (int r = 0; r < 4; ++r) acc[r] = (f4)0.f;
        for (int j4 = 0; j4 < 16; ++j4) {
            f4 ak[4], bs[4];
            #pragma unroll
            for (int r = 0; r < 4; ++r)  ak[r] = *(const f4*)(Wkh + (di * 4 + r) * D + j4 * 4);
            #pragma unroll
            for (int jj = 0; jj < 4; ++jj) bs[jj] = *(const f4*)(Sb + (j4 * 4 + jj) * D + ej * 4);
            #pragma unroll
            for (int r = 0; r < 4; ++r)
                #pragma unroll
                for (int jj = 0; jj < 4; ++jj)
                    acc[r] += ak[r][jj] * bs[jj];
        }
        #pragma unroll
        for (int r = 0; r < 4; ++r)
            #pragma unroll
            for (int c = 0; c < 4; ++c)
                T[(di * 4 + r) * 65 + ej * 4 + ((c + di) & 3)] = acc[r][c];
    }
    __syncthreads();

    // m2: U[d][e] = sum_i T[d][i] * Wk_h[e][i]
    {
        float a2[4][4];
        #pragma unroll
        for (int r = 0; r < 4; ++r)
            #pragma unroll
            for (int c = 0; c < 4; ++c) a2[r][c] = 0.f;
        for (int i4 = 0; i4 < 16; ++i4) {
            float av[4][4];
            f4 bw[4];
            #pragma unroll
            for (int ii = 0; ii < 4; ++ii)
                #pragma unroll
                for (int r = 0; r < 4; ++r)
                    av[r][ii] = T[(di * 4 + r) * 65 + i4 * 4 + ((ii + di) & 3)];
            #pragma unroll
            for (int c = 0; c < 4; ++c)
                bw[c] = *(const f4*)(Wkh + (ej * 4 + c) * D + i4 * 4);
            #pragma unroll
            for (int r = 0; r < 4; ++r)
                #pragma unroll
                for (int c = 0; c < 4; ++c)
                    #pragma unroll
                    for (int ii = 0; ii < 4; ++ii)
                        a2[r][c] = fmaf(av[r][ii], bw[c][ii], a2[r][c]);
        }
        #pragma unroll
        for (int r = 0; r < 4; ++r)
            #pragma unroll
            for (int c = 0; c < 4; ++c)
                U[(di * 4 + r) * 65 + ej * 4 + ((c + di) & 3)] = a2[r][c];
    }
    __syncthreads();

    // m3: M3[d][e] = sum_i Wq[64h+i][d] * U[i][e]  -> overwrite T
    {
        float acc[4][4];
        #pragma unroll
        for (int r = 0; r < 4; ++r)
            #pragma unroll
            for (int c = 0; c < 4; ++c) acc[r][c] = 0.f;
        for (int i4 = 0; i4 < 16; ++i4) {
            f4 wq4[4];
            float bu[4][4];
            #pragma unroll
            for (int ii = 0; ii < 4; ++ii) {
                wq4[ii] = *(const f4*)(Wq + (size_t)(64 * h + i4 * 4 + ii) * D + di * 4);
                #pragma unroll
                for (int c = 0; c < 4; ++c)
                    bu[ii][c] = U[(i4 * 4 + ii) * 65 + ej * 4 + ((c + i4) & 3)];
            }
            #pragma unroll
            for (int r = 0; r < 4; ++r)
                #pragma unroll
                for (int c = 0; c < 4; ++c)
                    #pragma unroll
                    for (int ii = 0; ii < 4; ++ii)
                        acc[r][c] = fmaf(wq4[ii][r], bu[ii][c], acc[r][c]);
        }
        __syncthreads();   // m2 readers of T are done (they sync'd above); WAR-safe rewrite
        #pragma unroll
        for (int r = 0; r < 4; ++r)
            #pragma unroll
            for (int c = 0; c < 4; ++c)
                T[(di * 4 + r) * 65 + ej * 4 + ((c + di) & 3)] = acc[r][c];
    }
    __syncthreads();

    // m4: Y[d][e] = sum_i M3[d][i] * Wout[e][64h+i]; GT[e][d] += Y/N
    {
        float a2[4][4];
        #pragma unroll
        for (int r = 0; r < 4; ++r)
            #pragma unroll
            for (int c = 0; c < 4; ++c) a2[r][c] = 0.f;
        for (int i4 = 0; i4 < 16; ++i4) {
            float av[4][4];
            f4 bw[4];
            #pragma unroll
            for (int ii = 0; ii < 4; ++ii)
                #pragma unroll
                for (int r = 0; r < 4; ++r)
                    av[r][ii] = T[(di * 4 + r) * 65 + i4 * 4 + ((ii + di) & 3)];
            #pragma unroll
            for (int c = 0; c < 4; ++c)
                bw[c] = *(const f4*)(Wout + (size_t)(ej * 4 + c) * INNER + 64 * h + i4 * 4);
            #pragma unroll
            for (int r = 0; r < 4; ++r)
                #pragma unroll
                for (int c = 0; c < 4; ++c)
                    #pragma unroll
                    for (int ii = 0; ii < 4; ++ii)
                        a2[r][c] = fmaf(av[r][ii], bw[c][ii], a2[r][c]);
        }
        const float invn = 1.0f / (float)SEQ;
        float* GTb = ws + OFF_GT + b * 4096;
        #pragma unroll
        for (int r = 0; r < 4; ++r)
            #pragma unroll
            for (int c = 0; c < 4; ++c)
                atomicAdd(&GTb[(ej * 4 + c) * 64 + di * 4 + r], a2[r][c] * invn);
    }
}

// ---------------------------------------------------------------------------
// kE: out[n][e] = q[n][:] . G[:][e] + bout[e] via GT. 2048 blocks x 32 rows,
// no LDS, VGPR ~45 -> 8 blocks/CU (32 waves/CU). Thread: 2 rows x 4 cols.
// ---------------------------------------------------------------------------
__global__ __launch_bounds__(256) void kE(const float* __restrict__ queries,
                                          const float* __restrict__ bout,
                                          const float* __restrict__ ws,
                                          float* __restrict__ out) {
    const int bid = blockIdx.x;
    const int b = bid >> 9;
    const int row0 = (bid & 511) * 32;
    const int t = threadIdx.x;
    const int rg = t >> 4;     // 0..15 -> rows rg*2, rg*2+1
    const int eg = t & 15;     // cols eg*4..+3
    const float* GT = ws + OFF_GT + b * 4096;
    const size_t rbase = (size_t)b * SEQ + row0 + rg * 2;
    const float* qp = queries + rbase * D;
    float acc[2][4];
    #pragma unroll
    for (int r = 0; r < 2; ++r)
        #pragma unroll
        for (int c = 0; c < 4; ++c) acc[r][c] = 0.f;
    #pragma unroll 4
    for (int dq = 0; dq < 16; ++dq) {
        f4 q0 = *(const f4*)(qp + dq * 4);
        f4 q1 = *(const f4*)(qp + D + dq * 4);
        f4 g4[4];
        #pragma unroll
        for (int c = 0; c < 4; ++c)
            g4[c] = *(const f4*)(GT + (eg * 4 + c) * 64 + dq * 4);
        #pragma unroll
        for (int c = 0; c < 4; ++c)
            #pragma unroll
            for (int ii = 0; ii < 4; ++ii) {
                acc[0][c] = fmaf(q0[ii], g4[c][ii], acc[0][c]);
                acc[1][c] = fmaf(q1[ii], g4[c][ii], acc[1][c]);
            }
    }
    const f4 bo = *(const f4*)(bout + eg * 4);
    float* op = out + rbase * D;
    #pragma unroll
    for (int r = 0; r < 2; ++r) {
        f4 o;
        o[0] = acc[r][0] + bo[0]; o[1] = acc[r][1] + bo[1];
        o[2] = acc[r][2] + bo[2]; o[3] = acc[r][3] + bo[3];
        *(f4*)(op + r * D + eg * 4) = o;
    }
}

extern "C" void kernel_launch(void* const* d_in, const int* in_sizes, int n_in,
                              void* d_out, int out_size, void* d_ws, size_t ws_size,
                              hipStream_t stream) {
    const float* queries = (const float*)d_in[0];
    const float* keys    = (const float*)d_in[1];
    const float* values  = (const float*)d_in[2];
    const float* Wq      = (const float*)d_in[3];
    const float* Wk      = (const float*)d_in[4];
    const float* Wout    = (const float*)d_in[5];
    const float* bout    = (const float*)d_in[6];
    float* ws = (float*)d_ws;

    // zero S + GT (atomic accumulation targets)
    hipMemsetAsync(ws, 0, (size_t)2 * NB * 4096 * sizeof(float), stream);

    kA<<<2048, 256, 0, stream>>>(keys, values, ws + OFF_PART);
    kB<<<256,  256, 0, stream>>>(ws + OFF_PART, ws + OFF_S);
    kC<<<32,   256, 0, stream>>>(Wq, Wk, Wout, ws);
    kE<<<2048, 256, 0, stream>>>(queries, bout, ws, (float*)d_out);
}

// Round 11
// 154.541 us; speedup vs baseline: 1.3952x; 1.3952x over previous
//
#include <hip/hip_runtime.h>

#define NB 4
#define SEQ 16384
#define D 64
#define NH 8
#define INNER 512

typedef float f4 __attribute__((ext_vector_type(4)));

// ws float-offsets
#define OFF_S    0                 // [NB][64][64]   S = K^T V
#define OFF_GT   (NB * 4096)       // [NB][64][64]   GT[e][d] = G[d][e]
#define OFF_PART (2 * NB * 4096)   // [512][4096]    per-block K^T V partials

// ---------------------------------------------------------------------------
// kA: column-in-VGPR K^T V. 512 blocks (128 rows each), 256 thr = 4 waves.
// Lane e owns S[:,e] in 16 f4 regs. k-tile staged in LDS (coalesced f4),
// read back wave-uniform (broadcast, conflict-free). v loads lane-consecutive
// (coalesced 256 B). 4 waves reduce via LDS; one 16 KB partial per block.
// ---------------------------------------------------------------------------
__global__ __launch_bounds__(256) void kA(const float* __restrict__ keys,
                                          const float* __restrict__ values,
                                          float* __restrict__ part) {
    __shared__ float kt[128 * 64];   // 32 KB k-tile
    __shared__ float red[64 * 64];   // 16 KB reduce buffer
    const int bid = blockIdx.x;      // 512 blocks, 128/batch
    const int b = bid >> 7;
    const int row0 = (bid & 127) * 128;
    const int t = threadIdx.x;
    const int w = t >> 6, e = t & 63;

    // stage k-tile: 2048 f4, 8 per thread, coalesced
    {
        const f4* src = (const f4*)(keys + ((size_t)b * SEQ + row0) * D);
        f4* dst = (f4*)kt;
        #pragma unroll
        for (int i = 0; i < 8; ++i)
            dst[t + 256 * i] = src[t + 256 * i];
    }
    __syncthreads();

    // wave w: rows w*32 .. w*32+31
    f4 acc[16];
    #pragma unroll
    for (int i = 0; i < 16; ++i) acc[i] = (f4)0.f;
    const float* vp = values + ((size_t)b * SEQ + row0 + w * 32) * D + e;
    #pragma unroll 8
    for (int n = 0; n < 32; ++n) {
        const float ve = vp[n * D];                 // coalesced 256 B
        const float* krow = kt + (w * 32 + n) * D;  // wave-uniform -> broadcast
        #pragma unroll
        for (int dq = 0; dq < 16; ++dq) {
            f4 k4 = *(const f4*)(krow + dq * 4);
            acc[dq] += k4 * ve;
        }
    }

    // sequential cross-wave reduce into red[d*64+e] (lane-consecutive, no conflicts)
    for (int ph = 0; ph < 4; ++ph) {
        if (w == ph) {
            if (ph == 0) {
                #pragma unroll
                for (int dq = 0; dq < 16; ++dq)
                    #pragma unroll
                    for (int ii = 0; ii < 4; ++ii)
                        red[(dq * 4 + ii) * 64 + e] = acc[dq][ii];
            } else {
                #pragma unroll
                for (int dq = 0; dq < 16; ++dq)
                    #pragma unroll
                    for (int ii = 0; ii < 4; ++ii)
                        red[(dq * 4 + ii) * 64 + e] += acc[dq][ii];
            }
        }
        __syncthreads();
    }

    // store 16 KB partial, coalesced f4
    {
        const f4* rsrc = (const f4*)red;
        f4* pdst = (f4*)(part + (size_t)bid * 4096);
        #pragma unroll
        for (int i = 0; i < 4; ++i)
            pdst[i * 256 + t] = rsrc[i * 256 + t];
    }
}

// ---------------------------------------------------------------------------
// kB: reduce 128 partials/batch -> S[b]. 128 blocks = (b, quarter, p-chunk).
// Block sums 16 partials over 1024 elems (f4/thread), then 4 scalar
// atomicAdds/thread into S (8-way contention, 131k atomics total).
// ---------------------------------------------------------------------------
__global__ __launch_bounds__(256) void kB(const float* __restrict__ part,
                                          float* __restrict__ S) {
    const int bid = blockIdx.x;
    const int b  = bid >> 5;
    const int q  = (bid >> 3) & 3;
    const int pc = bid & 7;
    const int t = threadIdx.x;
    const int e0 = q * 1024 + t * 4;
    const float* pp = part + (size_t)(b * 128 + pc * 16) * 4096 + e0;
    f4 s = (f4)0.f;
    #pragma unroll 8
    for (int p = 0; p < 16; ++p)
        s += *(const f4*)(pp + (size_t)p * 4096);
    float* Sb = S + b * 4096 + e0;
    #pragma unroll
    for (int i = 0; i < 4; ++i)
        atomicAdd(&Sb[i], s[i]);
}

// ---------------------------------------------------------------------------
// kC: merged small-matmul chain. One block per (b,h), 256 thr, 16x16 grid of
// 4x4 tiles. m1: T=Wk_h S; m2: U=T Wk_h^T; m3: M3=Wq_h^T U (overwrite T);
// m4: GT[b] += (1/N)*(M3 Wout_h^T)^T (atomicAdd, 8-way over h).
// LDS stride-65 + rotated columns (<=2-way banks = free).
// ---------------------------------------------------------------------------
__global__ __launch_bounds__(256) void kC(const float* __restrict__ Wq,
                                          const float* __restrict__ Wk,
                                          const float* __restrict__ Wout,
                                          float* __restrict__ ws) {
    __shared__ float T[64 * 65];
    __shared__ float U[64 * 65];
    const int b = blockIdx.x >> 3, h = blockIdx.x & 7;
    const int t = threadIdx.x;
    const int di = t >> 4, ej = t & 15;
    const float* Sb  = ws + OFF_S + b * 4096;
    const float* Wkh = Wk + (size_t)h * 64 * D;

    // m1: T[d][i] = sum_j Wk_h[d][j] * S[j][i]
    {
        f4 acc[4];
        #pragma unroll
        for (int r = 0; r < 4; ++r) acc[r] = (f4)0.f;
        for (int j4 = 0; j4 < 16; ++j4) {
            f4 ak[4], bs[4];
            #pragma unroll
            for (int r = 0; r < 4; ++r)  ak[r] = *(const f4*)(Wkh + (di * 4 + r) * D + j4 * 4);
            #pragma unroll
            for (int jj = 0; jj < 4; ++jj) bs[jj] = *(const f4*)(Sb + (j4 * 4 + jj) * D + ej * 4);
            #pragma unroll
            for (int r = 0; r < 4; ++r)
                #pragma unroll
                for (int jj = 0; jj < 4; ++jj)
                    acc[r] += ak[r][jj] * bs[jj];
        }
        #pragma unroll
        for (int r = 0; r < 4; ++r)
            #pragma unroll
            for (int c = 0; c < 4; ++c)
                T[(di * 4 + r) * 65 + ej * 4 + ((c + di) & 3)] = acc[r][c];
    }
    __syncthreads();

    // m2: U[d][e] = sum_i T[d][i] * Wk_h[e][i]
    {
        float a2[4][4];
        #pragma unroll
        for (int r = 0; r < 4; ++r)
            #pragma unroll
            for (int c = 0; c < 4; ++c) a2[r][c] = 0.f;
        for (int i4 = 0; i4 < 16; ++i4) {
            float av[4][4];
            f4 bw[4];
            #pragma unroll
            for (int ii = 0; ii < 4; ++ii)
                #pragma unroll
                for (int r = 0; r < 4; ++r)
                    av[r][ii] = T[(di * 4 + r) * 65 + i4 * 4 + ((ii + di) & 3)];
            #pragma unroll
            for (int c = 0; c < 4; ++c)
                bw[c] = *(const f4*)(Wkh + (ej * 4 + c) * D + i4 * 4);
            #pragma unroll
            for (int r = 0; r < 4; ++r)
                #pragma unroll
                for (int c = 0; c < 4; ++c)
                    #pragma unroll
                    for (int ii = 0; ii < 4; ++ii)
                        a2[r][c] = fmaf(av[r][ii], bw[c][ii], a2[r][c]);
        }
        #pragma unroll
        for (int r = 0; r < 4; ++r)
            #pragma unroll
            for (int c = 0; c < 4; ++c)
                U[(di * 4 + r) * 65 + ej * 4 + ((c + di) & 3)] = a2[r][c];
    }
    __syncthreads();

    // m3: M3[d][e] = sum_i Wq[64h+i][d] * U[i][e]  -> overwrite T
    {
        float acc[4][4];
        #pragma unroll
        for (int r = 0; r < 4; ++r)
            #pragma unroll
            for (int c = 0; c < 4; ++c) acc[r][c] = 0.f;
        for (int i4 = 0; i4 < 16; ++i4) {
            f4 wq4[4];
            float bu[4][4];
            #pragma unroll
            for (int ii = 0; ii < 4; ++ii) {
                wq4[ii] = *(const f4*)(Wq + (size_t)(64 * h + i4 * 4 + ii) * D + di * 4);
                #pragma unroll
                for (int c = 0; c < 4; ++c)
                    bu[ii][c] = U[(i4 * 4 + ii) * 65 + ej * 4 + ((c + i4) & 3)];
            }
            #pragma unroll
            for (int r = 0; r < 4; ++r)
                #pragma unroll
                for (int c = 0; c < 4; ++c)
                    #pragma unroll
                    for (int ii = 0; ii < 4; ++ii)
                        acc[r][c] = fmaf(wq4[ii][r], bu[ii][c], acc[r][c]);
        }
        __syncthreads();
        #pragma unroll
        for (int r = 0; r < 4; ++r)
            #pragma unroll
            for (int c = 0; c < 4; ++c)
                T[(di * 4 + r) * 65 + ej * 4 + ((c + di) & 3)] = acc[r][c];
    }
    __syncthreads();

    // m4: Y[d][e] = sum_i M3[d][i] * Wout[e][64h+i]; GT[e][d] += Y/N
    {
        float a2[4][4];
        #pragma unroll
        for (int r = 0; r < 4; ++r)
            #pragma unroll
            for (int c = 0; c < 4; ++c) a2[r][c] = 0.f;
        for (int i4 = 0; i4 < 16; ++i4) {
            float av[4][4];
            f4 bw[4];
            #pragma unroll
            for (int ii = 0; ii < 4; ++ii)
                #pragma unroll
                for (int r = 0; r < 4; ++r)
                    av[r][ii] = T[(di * 4 + r) * 65 + i4 * 4 + ((ii + di) & 3)];
            #pragma unroll
            for (int c = 0; c < 4; ++c)
                bw[c] = *(const f4*)(Wout + (size_t)(ej * 4 + c) * INNER + 64 * h + i4 * 4);
            #pragma unroll
            for (int r = 0; r < 4; ++r)
                #pragma unroll
                for (int c = 0; c < 4; ++c)
                    #pragma unroll
                    for (int ii = 0; ii < 4; ++ii)
                        a2[r][c] = fmaf(av[r][ii], bw[c][ii], a2[r][c]);
        }
        const float invn = 1.0f / (float)SEQ;
        float* GTb = ws + OFF_GT + b * 4096;
        #pragma unroll
        for (int r = 0; r < 4; ++r)
            #pragma unroll
            for (int c = 0; c < 4; ++c)
                atomicAdd(&GTb[(ej * 4 + c) * 64 + di * 4 + r], a2[r][c] * invn);
    }
}

// ---------------------------------------------------------------------------
// kE: column-in-VGPR apply. 1024 blocks (64 rows each), 256 thr = 4 waves.
// Lane e holds G[:,e] in 16 f4 regs (loaded once). q tile staged in LDS
// (coalesced), read wave-uniform (broadcast). out stores lane-consecutive.
// ---------------------------------------------------------------------------
__global__ __launch_bounds__(256) void kE(const float* __restrict__ queries,
                                          const float* __restrict__ bout,
                                          const float* __restrict__ ws,
                                          float* __restrict__ out) {
    __shared__ float qs[64 * 64];    // 16 KB
    const int bid = blockIdx.x;      // 1024 blocks, 256/batch
    const int b = bid >> 8;
    const int row0 = (bid & 255) * 64;
    const int t = threadIdx.x;
    const int w = t >> 6, e = t & 63;

    // stage q tile: 1024 f4, 4 per thread, coalesced
    {
        const f4* src = (const f4*)(queries + ((size_t)b * SEQ + row0) * D);
        f4* dst = (f4*)qs;
        #pragma unroll
        for (int i = 0; i < 4; ++i)
            dst[t + 256 * i] = src[t + 256 * i];
    }
    // G column e -> 16 f4 regs (GT is e-major, so per-lane contiguous reads)
    const float* GT = ws + OFF_GT + b * 4096 + e * 64;
    f4 g[16];
    #pragma unroll
    for (int dq = 0; dq < 16; ++dq)
        g[dq] = *(const f4*)(GT + dq * 4);
    const float be = bout[e];
    __syncthreads();

    float* op = out + ((size_t)b * SEQ + row0 + w * 16) * D + e;
    #pragma unroll 2
    for (int r = 0; r < 16; ++r) {
        const float* qrow = qs + (w * 16 + r) * D;   // wave-uniform -> broadcast
        f4 a4 = (f4)0.f;
        #pragma unroll
        for (int dq = 0; dq < 16; ++dq) {
            f4 q4 = *(const f4*)(qrow + dq * 4);
            a4 += q4 * g[dq];
        }
        op[r * D] = a4[0] + a4[1] + a4[2] + a4[3] + be;   // coalesced 256 B
    }
}

extern "C" void kernel_launch(void* const* d_in, const int* in_sizes, int n_in,
                              void* d_out, int out_size, void* d_ws, size_t ws_size,
                              hipStream_t stream) {
    const float* queries = (const float*)d_in[0];
    const float* keys    = (const float*)d_in[1];
    const float* values  = (const float*)d_in[2];
    const float* Wq      = (const float*)d_in[3];
    const float* Wk      = (const float*)d_in[4];
    const float* Wout    = (const float*)d_in[5];
    const float* bout    = (const float*)d_in[6];
    float* ws = (float*)d_ws;

    // zero S + GT (atomic accumulation targets)
    hipMemsetAsync(ws, 0, (size_t)2 * NB * 4096 * sizeof(float), stream);

    kA<<<512,  256, 0, stream>>>(keys, values, ws + OFF_PART);
    kB<<<128,  256, 0, stream>>>(ws + OFF_PART, ws + OFF_S);
    kC<<<32,   256, 0, stream>>>(Wq, Wk, Wout, ws);
    kE<<<1024, 256, 0, stream>>>(queries, bout, ws, (float*)d_out);
}